// Round 6
// baseline (1342.616 us; speedup 1.0000x reference)
//
#include <hip/hip_runtime.h>
#include <hip/hip_bf16.h>
#include <stdint.h>

// Problem constants
#define NB 64      // batch
#define NT 128     // seq len
#define NE 512     // embed
#define NH 1024    // hidden
#define NV 32000   // vocab
#define NM (NB*NT) // 8192 flattened (t-major: m = t*64 + b)
#define NBNH (NB*NH)

// Kernel config
#define NWG 256    // one workgroup per CU, all co-resident
#define NTH 512    // 8 waves
#define FLAG_STRIDE 32u   // one flag per 128-B LLC line

// ws layout. History slots write-once per launch, FRAGMENT-MAJOR:
// element (rb,kk,lane,j) at ((rb*32+kk)*64+lane)*8+j holds
// h[rb*16+(lane&15)][kk*32+(lane>>4)*8+j].
#define HSLOT_B (NB*NH*2u)                      // 131072 B per history slot
#define WS_FLAGS_S 0u
#define WS_FLAGS_A (32u*1024u)
#define WS_FLAGS_B (64u*1024u)
#define WS_H0      (96u*1024u)
#define WS_H1      (WS_H0 + 129u*HSLOT_B)
#define WS_CNT     (WS_H1 + 129u*HSLOT_B)
#define WS_XS0     (WS_CNT + 4u*NB*NV)
#define WS_NEEDED  (WS_XS0 + 2u*NM*NE)

typedef __attribute__((ext_vector_type(8))) short bf16x8;
typedef __attribute__((ext_vector_type(4))) float f32x4;

#define SCOPE_WG  __HIP_MEMORY_SCOPE_WORKGROUP
#define SCOPE_AG  __HIP_MEMORY_SCOPE_AGENT

// compiler+scheduler fence (no HW cost)
#define FENCE() do { asm volatile("" ::: "memory"); __builtin_amdgcn_sched_barrier(0); } while (0)
// wave-wide LDS drain: all 64 lanes' ds ops done before anything after (rule #18)
#define LGKM0() do { asm volatile("s_waitcnt lgkmcnt(0)" ::: "memory"); __builtin_amdgcn_sched_barrier(0); } while (0)
// wave-wide VMEM drain: sc1 stores acked at LLC
#define VM0()   do { asm volatile("s_waitcnt vmcnt(0)" ::: "memory"); __builtin_amdgcn_sched_barrier(0); } while (0)

__device__ __forceinline__ unsigned short f2bf(float f) {
  unsigned u = __float_as_uint(f);
  u += 0x7FFFu + ((u >> 16) & 1u);   // round-nearest-even
  return (unsigned short)(u >> 16);
}
__device__ __forceinline__ float sigmoidf_(float x) {
  return 1.0f / (1.0f + expf(-x));
}
__device__ __forceinline__ bf16x8 pack8(float4 a, float4 b) {
  bf16x8 v;
  v[0]=(short)f2bf(a.x); v[1]=(short)f2bf(a.y); v[2]=(short)f2bf(a.z); v[3]=(short)f2bf(a.w);
  v[4]=(short)f2bf(b.x); v[5]=(short)f2bf(b.y); v[6]=(short)f2bf(b.z); v[7]=(short)f2bf(b.w);
  return v;
}

// wg-wide grid barrier (used only at startup / pre-FC, where __syncthreads is fine)
__device__ __forceinline__ void gbar_light(unsigned* flags, unsigned n) {
  __syncthreads();
  if (threadIdx.x == 0)
    __hip_atomic_store(&flags[(unsigned)blockIdx.x * FLAG_STRIDE], n, __ATOMIC_RELAXED, SCOPE_AG);
  if (threadIdx.x < NWG) {
    while (__hip_atomic_load(&flags[(unsigned)threadIdx.x * FLAG_STRIDE], __ATOMIC_RELAXED, SCOPE_AG) < n)
      __builtin_amdgcn_s_sleep(8);
  }
  __syncthreads();
}

#define MFMA(a,b,c) __builtin_amdgcn_mfma_f32_16x16x32_bf16((a),(b),(c),0,0,0)

__global__ void __launch_bounds__(NTH, 2)
lstm_all(const int* __restrict__ x, const float* __restrict__ emb,
         const float* __restrict__ w_ih0, const float* __restrict__ w_hh0,
         const float* __restrict__ b_ih0, const float* __restrict__ b_hh0,
         const float* __restrict__ w_ih1, const float* __restrict__ w_hh1,
         const float* __restrict__ b_ih1, const float* __restrict__ b_hh1,
         const float* __restrict__ fc_w, const float* __restrict__ fc_b,
         float* __restrict__ out, unsigned char* __restrict__ wsb)
{
  __shared__ unsigned short sWih1[32*64*8];            // 32 KB, fragment order
  __shared__ unsigned short sWih0[16*64*8];            // 16 KB, fragment order
  __shared__ float sG0[NB][16], sGih[NB][16], sG1b[NB][16];
  __shared__ float ringP[4][NB][16];                   // a1 ring: chain0 -> chain1
  __shared__ float sB0[16], sB1[16];
  __shared__ alignas(8) unsigned short sH0[NB][4], sH1[NB][4];
  // cumulative counters: [0..3]=prodA[w], [4..7]=consB[w], [8]=doneA, [9]=doneB,
  // [10]=syncA arrivals, [11]=syncB arrivals
  __shared__ unsigned ldsCnt[12];

  const int wg  = blockIdx.x;
  const int tid = threadIdx.x;
  const int wave = tid >> 6, lane = tid & 63;
  const int lr = lane & 15, lq = lane >> 4;

  unsigned* flagsS = (unsigned*)(wsb + WS_FLAGS_S);
  unsigned* flagsA = (unsigned*)(wsb + WS_FLAGS_A);
  unsigned* flagsB = (unsigned*)(wsb + WS_FLAGS_B);
  unsigned short* hist0 = (unsigned short*)(wsb + WS_H0);
  unsigned short* hist1 = (unsigned short*)(wsb + WS_H1);
  unsigned* counts = (unsigned*)(wsb + WS_CNT);
  unsigned short* xs0 = (unsigned short*)(wsb + WS_XS0);

  // gate-row this lane's B-fragments correspond to: gate=(lr>>2), unit=(lr&3)
  const int gr = (lr >> 2)*NH + wg*4 + (lr & 3);

  // fragment-major publish offset for this wg's 4 units; batch row b = w*16+l
  const unsigned kkw = (unsigned)wg >> 3, lqw = ((unsigned)wg >> 1) & 3, j0 = ((unsigned)wg & 1)*4;

  if (tid < 12) ldsCnt[tid] = 0;

  // ---- phase 1a: step-invariant B-fragments of w_hh0 (waves 0-3) or w_hh1
  // (waves 4-7) into 128 VGPRs.
  bf16x8 breg[32];
  {
    const float* wsrc = (wave < 4 ? w_hh0 : w_hh1) + (size_t)gr*NH + lq*8;
    #pragma unroll
    for (int kk = 0; kk < 32; ++kk)
      breg[kk] = pack8(*(const float4*)(wsrc + kk*32), *(const float4*)(wsrc + kk*32 + 4));
  }

  // ---- phase 1b: gather embeddings -> xs0 (bf16, fragment-major), sc1
  for (int i = wg*NTH + tid; i < NM*(NE/8); i += NWG*NTH) {
    int m = i >> 6;
    int e8 = (i & 63) << 3;
    int t = m >> 6, b = m & 63;
    int tok = x[b*NT + t];
    const float* s = emb + (size_t)tok*NE + e8;
    union { bf16x8 v8; unsigned long long u[2]; } u;
    u.v8 = pack8(*(const float4*)s, *(const float4*)(s + 4));
    int mblk = m >> 4, lrm = m & 15;
    int kk = e8 >> 5, lqm = (e8 >> 3) & 3;
    size_t elem = ((size_t)(mblk*16 + kk)*64 + lqm*16 + lrm) * 8;
    unsigned long long* dst = (unsigned long long*)(xs0 + elem);
    __hip_atomic_store(dst,   u.u[0], __ATOMIC_RELAXED, SCOPE_AG);
    __hip_atomic_store(dst+1, u.u[1], __ATOMIC_RELAXED, SCOPE_AG);
  }

  // ---- phase 1c: w_ih1 / w_ih0 slices -> LDS in fragment order
  for (int i = tid; i < 32*64; i += NTH) {
    int kk = i >> 6, l = i & 63;
    int glr = l & 15, glq = l >> 4;
    int ggr = (glr >> 2)*NH + wg*4 + (glr & 3);
    const float* p = w_ih1 + (size_t)ggr*NH + kk*32 + glq*8;
    ((bf16x8*)sWih1)[i] = pack8(*(const float4*)p, *(const float4*)(p + 4));
  }
  for (int i = tid; i < 16*64; i += NTH) {
    int kk = i >> 6, l = i & 63;
    int glr = l & 15, glq = l >> 4;
    int ggr = (glr >> 2)*NH + wg*4 + (glr & 3);
    const float* p = w_ih0 + (size_t)ggr*NE + kk*32 + glq*8;
    ((bf16x8*)sWih0)[i] = pack8(*(const float4*)p, *(const float4*)(p + 4));
  }
  if (tid < 16) {
    int g2 = (tid >> 2)*NH + wg*4 + (tid & 3);
    sB0[tid] = b_ih0[g2] + b_hh0[g2];
    sB1[tid] = b_ih1[g2] + b_hh1[g2];
  }
  // ---- phase 1d: token histogram
  {
    int i = wg*NTH + tid;
    if (i < NB*NT) {
      int b = i >> 7;
      atomicAdd(&counts[(size_t)b*NV + x[i]], 1u);
    }
  }
  gbar_light(flagsS, 1);

  // ================= scan: two decoupled chains, no __syncthreads =================
  const int cbl = lane >> 2, cu = lane & 3;           // cell mapping within a wave

  if (wave < 4) {
    // ---------- chain0 (layer 0): waves 0-3, flagsA, hist0 ----------
    const int w = wave;
    const size_t pubOffW = ((size_t)(w*32 + kkw)*64 + lqw*16 + lane)*8 + j0; // lane<16
    float c0 = 0.f;
    for (int t = 0; t <= NT; ++t) {
      // wait: all wgs published hist0 slot t (flagA >= t); wave covers 64 wgs
      while (__hip_atomic_load(&flagsA[(unsigned)(w*64 + lane)*FLAG_STRIDE],
                               __ATOMIC_RELAXED, SCOPE_AG) < (unsigned)t)
        __builtin_amdgcn_s_sleep(1);
      if (lane == 0) {
        __hip_atomic_fetch_add(&ldsCnt[10], 1u, __ATOMIC_ACQ_REL, SCOPE_WG);
        while (__hip_atomic_load(&ldsCnt[10], __ATOMIC_ACQUIRE, SCOPE_WG) < 4u*(unsigned)(t+1)) {}
      }
      FENCE();
      // ring overwrite guard: chain1 must have consumed slot t&3
      if (t >= 4) {
        if (lane == 0)
          while (__hip_atomic_load(&ldsCnt[4+w], __ATOMIC_ACQUIRE, SCOPE_WG) < (unsigned)(t-3)) {}
        FENCE();
      }
      // MFMA: a0 = h0[t-1]@w_hh0 (regs), a1 = h0[t-1]@w_ih1 (LDS), aih = xs0[t]@w_ih0
      const unsigned short* A = hist0 + (size_t)t*NBNH + (size_t)(w*2048 + lane)*8;
      f32x4 a0 = {0.f,0.f,0.f,0.f}, a1 = {0.f,0.f,0.f,0.f}, ai = {0.f,0.f,0.f,0.f};
      if (t < NT) {
        #pragma unroll
        for (int kk = 0; kk < 32; ++kk) {
          bf16x8 af = *(const bf16x8*)(A + kk*512);
          a0 = MFMA(af, breg[kk], a0);
          a1 = MFMA(af, ((const bf16x8*)sWih1)[kk*64 + lane], a1);
        }
        const unsigned short* X = xs0 + ((size_t)(t*4 + w)*1024 + lane)*8;
        #pragma unroll
        for (int kk = 0; kk < 16; ++kk)
          ai = MFMA(*(const bf16x8*)(X + kk*512), ((const bf16x8*)sWih0)[kk*64 + lane], ai);
      } else {
        #pragma unroll
        for (int kk = 0; kk < 32; ++kk)
          a1 = MFMA(*(const bf16x8*)(A + kk*512), ((const bf16x8*)sWih1)[kk*64 + lane], a1);
      }
      // stage results to LDS (intra-wave transpose)
      {
        int rs = t & 3;
        #pragma unroll
        for (int r = 0; r < 4; ++r) ringP[rs][w*16 + lq*4 + r][lr] = a1[r];
      }
      if (t < NT) {
        #pragma unroll
        for (int r = 0; r < 4; ++r) {
          sG0 [w*16 + lq*4 + r][lr] = a0[r];
          sGih[w*16 + lq*4 + r][lr] = ai[r];
        }
      }
      LGKM0();
      if (lane == 0)
        __hip_atomic_fetch_add(&ldsCnt[w], 1u, __ATOMIC_RELEASE, SCOPE_WG);  // prodA = t+1
      if (t < NT) {
        // cell0 for batch w*16+cbl, unit cu
        int cb = w*16 + cbl;
        float gi = sG0[cb][cu]    + sGih[cb][cu]    + sB0[cu];
        float gf = sG0[cb][4+cu]  + sGih[cb][4+cu]  + sB0[4+cu];
        float gg = sG0[cb][8+cu]  + sGih[cb][8+cu]  + sB0[8+cu];
        float go = sG0[cb][12+cu] + sGih[cb][12+cu] + sB0[12+cu];
        float ii = sigmoidf_(gi), ff = sigmoidf_(gf), g = tanhf(gg), oo = sigmoidf_(go);
        c0 = ff*c0 + ii*g;
        sH0[cb][cu] = f2bf(oo * tanhf(c0));
        LGKM0();
        if (lane < 16) {
          unsigned long long v = *(const unsigned long long*)&sH0[w*16 + lane][0];
          __hip_atomic_store((unsigned long long*)(hist0 + (size_t)(t+1)*NBNH + pubOffW),
                             v, __ATOMIC_RELAXED, SCOPE_AG);
        }
        VM0();
        if (lane == 0)
          __hip_atomic_fetch_add(&ldsCnt[8], 1u, __ATOMIC_RELEASE, SCOPE_WG); // doneA
        if (w == 0 && lane == 0) {
          while (__hip_atomic_load(&ldsCnt[8], __ATOMIC_ACQUIRE, SCOPE_WG) < 4u*(unsigned)(t+1)) {}
          __hip_atomic_store(&flagsA[(unsigned)wg*FLAG_STRIDE], (unsigned)(t+1),
                             __ATOMIC_RELAXED, SCOPE_AG);
        }
      }
    }
  } else {
    // ---------- chain1 (layer 1): waves 4-7, flagsB, hist1 ----------
    const int w1 = wave - 4;
    const size_t pubOffW = ((size_t)(w1*32 + kkw)*64 + lqw*16 + lane)*8 + j0; // lane<16
    float c1 = 0.f;
    for (int s = 0; s < NT; ++s) {
      while (__hip_atomic_load(&flagsB[(unsigned)(w1*64 + lane)*FLAG_STRIDE],
                               __ATOMIC_RELAXED, SCOPE_AG) < (unsigned)s)
        __builtin_amdgcn_s_sleep(1);
      if (lane == 0) {
        __hip_atomic_fetch_add(&ldsCnt[11], 1u, __ATOMIC_ACQ_REL, SCOPE_WG);
        while (__hip_atomic_load(&ldsCnt[11], __ATOMIC_ACQUIRE, SCOPE_WG) < 4u*(unsigned)(s+1)) {}
      }
      FENCE();
      // wait for ring slot (s+1)&3 (a1 for time s): prodA >= s+2
      if (lane == 0)
        while (__hip_atomic_load(&ldsCnt[w1], __ATOMIC_ACQUIRE, SCOPE_WG) < (unsigned)(s+2)) {}
      FENCE();
      // a2 = h1[s-1]@w_hh1 (regs)
      const unsigned short* A = hist1 + (size_t)s*NBNH + (size_t)(w1*2048 + lane)*8;
      f32x4 a2 = {0.f,0.f,0.f,0.f};
      #pragma unroll
      for (int kk = 0; kk < 32; ++kk)
        a2 = MFMA(*(const bf16x8*)(A + kk*512), breg[kk], a2);
      #pragma unroll
      for (int r = 0; r < 4; ++r) sG1b[w1*16 + lq*4 + r][lr] = a2[r];
      LGKM0();
      // cell1 for batch w1*16+cbl, unit cu
      {
        int cb = w1*16 + cbl;
        int rs = (s+1) & 3;
        float gi = ringP[rs][cb][cu]    + sG1b[cb][cu]    + sB1[cu];
        float gf = ringP[rs][cb][4+cu]  + sG1b[cb][4+cu]  + sB1[4+cu];
        float gg = ringP[rs][cb][8+cu]  + sG1b[cb][8+cu]  + sB1[8+cu];
        float go = ringP[rs][cb][12+cu] + sG1b[cb][12+cu] + sB1[12+cu];
        float ii = sigmoidf_(gi), ff = sigmoidf_(gf), g = tanhf(gg), oo = sigmoidf_(go);
        c1 = ff*c1 + ii*g;
        sH1[cb][cu] = f2bf(oo * tanhf(c1));
      }
      if (lane == 0)
        __hip_atomic_fetch_add(&ldsCnt[4+w1], 1u, __ATOMIC_RELEASE, SCOPE_WG); // consB = s+1
      LGKM0();
      if (lane < 16) {
        unsigned long long v = *(const unsigned long long*)&sH1[w1*16 + lane][0];
        __hip_atomic_store((unsigned long long*)(hist1 + (size_t)(s+1)*NBNH + pubOffW),
                           v, __ATOMIC_RELAXED, SCOPE_AG);
      }
      VM0();
      if (lane == 0)
        __hip_atomic_fetch_add(&ldsCnt[9], 1u, __ATOMIC_RELEASE, SCOPE_WG); // doneB
      if (w1 == 0 && lane == 0) {
        while (__hip_atomic_load(&ldsCnt[9], __ATOMIC_ACQUIRE, SCOPE_WG) < 4u*(unsigned)(s+1)) {}
        __hip_atomic_store(&flagsB[(unsigned)wg*FLAG_STRIDE], (unsigned)(s+1),
                           __ATOMIC_RELAXED, SCOPE_AG);
      }
    }
  }

  // wait for all wgs' chain1 to finish (hist1 slot 128 = h1[127] complete)
  __syncthreads();
  if (tid < NWG) {
    while (__hip_atomic_load(&flagsB[(unsigned)tid*FLAG_STRIDE], __ATOMIC_RELAXED, SCOPE_AG)
           < (unsigned)NT)
      __builtin_amdgcn_s_sleep(4);
  }
  __syncthreads();

  // ---- phase 4: FC + repetition penalty (h1[127] = hist1 slot 128, fragment-major) ----
  {
    const unsigned short* ab = hist1 + (size_t)128*NBNH + (size_t)lane*8;
    int tile = wg*8 + wave;                    // 2048 waves, 2000 col-tiles of 16
    if (tile < NV/16) {
      int c0 = tile*16;
      const float* wb = fc_w + (size_t)(c0 + lr)*NH + lq*8;
      f32x4 acc[4] = {{0.f,0.f,0.f,0.f},{0.f,0.f,0.f,0.f},{0.f,0.f,0.f,0.f},{0.f,0.f,0.f,0.f}};
      #pragma unroll 4
      for (int kk = 0; kk < 32; ++kk) {
        bf16x8 bfv = pack8(*(const float4*)(wb + kk*32), *(const float4*)(wb + kk*32 + 4));
        #pragma unroll
        for (int mt = 0; mt < 4; ++mt) {
          bf16x8 af = *(const bf16x8*)(ab + (size_t)(mt*32 + kk)*512);
          acc[mt] = MFMA(af, bfv, acc[mt]);
        }
      }
      int c = c0 + lr;
      float fb = fc_b[c];
      #pragma unroll
      for (int mt = 0; mt < 4; ++mt) {
        #pragma unroll
        for (int r = 0; r < 4; ++r) {
          int b = mt*16 + lq*4 + r;
          unsigned cnt = counts[(size_t)b*NV + c];
          float v = (acc[mt][r] + fb) * exp2f(-0.26303440583379378f * (float)cnt);
          out[(size_t)b*NV + c] = v;
        }
      }
    }
  }
}

extern "C" void kernel_launch(void* const* d_in, const int* in_sizes, int n_in,
                              void* d_out, int out_size, void* d_ws, size_t ws_size,
                              hipStream_t stream) {
  const int*   x     = (const int*)  d_in[0];
  const float* emb   = (const float*)d_in[1];
  const float* w_ih0 = (const float*)d_in[2];
  const float* w_hh0 = (const float*)d_in[3];
  const float* b_ih0 = (const float*)d_in[4];
  const float* b_hh0 = (const float*)d_in[5];
  const float* w_ih1 = (const float*)d_in[6];
  const float* w_hh1 = (const float*)d_in[7];
  const float* b_ih1 = (const float*)d_in[8];
  const float* b_hh1 = (const float*)d_in[9];
  const float* fc_w  = (const float*)d_in[10];
  const float* fc_b  = (const float*)d_in[11];
  if (ws_size < WS_NEEDED) return;
  unsigned char* ws = (unsigned char*)d_ws;
  hipMemsetAsync(ws, 0, WS_H0, stream);                        // flagsS/A/B
  hipMemsetAsync(ws + WS_H0, 0, HSLOT_B, stream);              // h0 init slot (zeros)
  hipMemsetAsync(ws + WS_H1, 0, HSLOT_B, stream);              // h1 init slot (zeros)
  hipMemsetAsync(ws + WS_CNT, 0, 4u*NB*NV, stream);            // token histogram
  hipLaunchKernelGGL(lstm_all, dim3(NWG), dim3(NTH), 0, stream,
                     x, emb, w_ih0, w_hh0, b_ih0, b_hh0,
                     w_ih1, w_hh1, b_ih1, b_hh1, fc_w, fc_b,
                     (float*)d_out, (unsigned char*)d_ws);
}

// Round 7
// 1253.800 us; speedup vs baseline: 1.0708x; 1.0708x over previous
//
#include <hip/hip_runtime.h>
#include <hip/hip_bf16.h>
#include <stdint.h>

// Problem constants
#define NB 64      // batch
#define NT 128     // seq len
#define NE 512     // embed
#define NH 1024    // hidden
#define NV 32000   // vocab
#define NM (NB*NT) // 8192 flattened (t-major: m = t*64 + b)
#define NBNH (NB*NH)

// Kernel config
#define NWG 256    // one workgroup per CU, all co-resident
#define NTH 512    // 8 waves
#define FLAG_STRIDE 32u   // one flag per 128-B LLC line

// ws layout. History slots write-once per launch, FRAGMENT-MAJOR:
// element (rb,kk,lane,j) at ((rb*32+kk)*64+lane)*8+j holds
// h[rb*16+(lane&15)][kk*32+(lane>>4)*8+j].
#define HSLOT_B (NB*NH*2u)                      // 131072 B per history slot
#define WS_FLAGS_S 0u
#define WS_FLAGS_A (32u*1024u)
#define WS_FLAGS_B (64u*1024u)
#define WS_H0      (96u*1024u)
#define WS_H1      (WS_H0 + 129u*HSLOT_B)
#define WS_CNT     (WS_H1 + 129u*HSLOT_B)
#define WS_XS0     (WS_CNT + 4u*NB*NV)
#define WS_NEEDED  (WS_XS0 + 2u*NM*NE)

typedef __attribute__((ext_vector_type(8))) short bf16x8;
typedef __attribute__((ext_vector_type(4))) float f32x4;

#define SCOPE_WG  __HIP_MEMORY_SCOPE_WORKGROUP
#define SCOPE_AG  __HIP_MEMORY_SCOPE_AGENT

// wave-wide LDS drain + scheduling fence (rule #18)
#define LGKM0() do { asm volatile("s_waitcnt lgkmcnt(0)" ::: "memory"); __builtin_amdgcn_sched_barrier(0); } while (0)
// wave-wide VMEM drain: sc1 stores acked at LLC
#define VM0()   do { asm volatile("s_waitcnt vmcnt(0)" ::: "memory"); __builtin_amdgcn_sched_barrier(0); } while (0)

__device__ __forceinline__ unsigned short f2bf(float f) {
  unsigned u = __float_as_uint(f);
  u += 0x7FFFu + ((u >> 16) & 1u);   // round-nearest-even
  return (unsigned short)(u >> 16);
}
__device__ __forceinline__ float sigmoidf_(float x) {
  return 1.0f / (1.0f + expf(-x));
}
__device__ __forceinline__ bf16x8 pack8(float4 a, float4 b) {
  bf16x8 v;
  v[0]=(short)f2bf(a.x); v[1]=(short)f2bf(a.y); v[2]=(short)f2bf(a.z); v[3]=(short)f2bf(a.w);
  v[4]=(short)f2bf(b.x); v[5]=(short)f2bf(b.y); v[6]=(short)f2bf(b.z); v[7]=(short)f2bf(b.w);
  return v;
}

// startup-only wg-wide grid barrier
__device__ __forceinline__ void gbar_light(unsigned* flags, unsigned n) {
  __syncthreads();
  if (threadIdx.x == 0)
    __hip_atomic_store(&flags[(unsigned)blockIdx.x * FLAG_STRIDE], n, __ATOMIC_RELAXED, SCOPE_AG);
  if (threadIdx.x < NWG) {
    while (__hip_atomic_load(&flags[(unsigned)threadIdx.x * FLAG_STRIDE], __ATOMIC_RELAXED, SCOPE_AG) < n)
      __builtin_amdgcn_s_sleep(8);
  }
  __syncthreads();
}

#define MFMA(a,b,c) __builtin_amdgcn_mfma_f32_16x16x32_bf16((a),(b),(c),0,0,0)

__global__ void __launch_bounds__(NTH, 2)
lstm_all(const int* __restrict__ x, const float* __restrict__ emb,
         const float* __restrict__ w_ih0, const float* __restrict__ w_hh0,
         const float* __restrict__ b_ih0, const float* __restrict__ b_hh0,
         const float* __restrict__ w_ih1, const float* __restrict__ w_hh1,
         const float* __restrict__ b_ih1, const float* __restrict__ b_hh1,
         const float* __restrict__ fc_w, const float* __restrict__ fc_b,
         float* __restrict__ out, unsigned char* __restrict__ wsb)
{
  __shared__ unsigned short sWih1[32*64*8];            // 32 KB, fragment order
  __shared__ unsigned short sWih0[16*64*8];            // 16 KB, fragment order
  __shared__ float sG0[NB][16], sGih[NB][16], sG1a[NB][16], sG1b[NB][16];
  __shared__ float sB0[16], sB1[16];
  __shared__ alignas(8) unsigned short sH0[NB][4], sH1[NB][4];
  __shared__ unsigned cntA, cntB;                      // cumulative publish arrivals

  const int wg  = blockIdx.x;
  const int tid = threadIdx.x;
  const int wave = tid >> 6, lane = tid & 63;
  const int lr = lane & 15, lq = lane >> 4;

  unsigned* flagsS = (unsigned*)(wsb + WS_FLAGS_S);
  unsigned* flagsA = (unsigned*)(wsb + WS_FLAGS_A);
  unsigned* flagsB = (unsigned*)(wsb + WS_FLAGS_B);
  unsigned short* hist0 = (unsigned short*)(wsb + WS_H0);
  unsigned short* hist1 = (unsigned short*)(wsb + WS_H1);
  unsigned* counts = (unsigned*)(wsb + WS_CNT);
  unsigned short* xs0 = (unsigned short*)(wsb + WS_XS0);

  // gate-row this lane's B-fragments correspond to: gate=(lr>>2), unit=(lr&3)
  const int gr = (lr >> 2)*NH + wg*4 + (lr & 3);

  // fragment-major publish offset pieces for this wg's 4 units
  const unsigned kkw = (unsigned)wg >> 3, lqw = ((unsigned)wg >> 1) & 3, j0 = ((unsigned)wg & 1)*4;
  // per-cell-wave publish offset (lane<16 = batch row within this wave's rowblock rb)
  const unsigned rbw = (unsigned)(wave & 3);
  const size_t pubOff = ((size_t)(rbw*32 + kkw)*64 + lqw*16 + lane)*8 + j0;

  if (tid == 0) { cntA = 0; cntB = 0; }

  // ---- phase 1a: step-invariant B-fragments of w_hh0 (waves 0-3) or w_hh1
  // (waves 4-7) into 128 VGPRs.
  bf16x8 breg[32];
  {
    const float* wsrc = (wave < 4 ? w_hh0 : w_hh1) + (size_t)gr*NH + lq*8;
    #pragma unroll
    for (int kk = 0; kk < 32; ++kk)
      breg[kk] = pack8(*(const float4*)(wsrc + kk*32), *(const float4*)(wsrc + kk*32 + 4));
  }

  // ---- phase 1b: gather embeddings -> xs0 (bf16, fragment-major), sc1
  for (int i = wg*NTH + tid; i < NM*(NE/8); i += NWG*NTH) {
    int m = i >> 6;
    int e8 = (i & 63) << 3;
    int t = m >> 6, b = m & 63;
    int tok = x[b*NT + t];
    const float* s = emb + (size_t)tok*NE + e8;
    union { bf16x8 v8; unsigned long long u[2]; } u;
    u.v8 = pack8(*(const float4*)s, *(const float4*)(s + 4));
    int mblk = m >> 4, lrm = m & 15;
    int kk = e8 >> 5, lqm = (e8 >> 3) & 3;
    size_t elem = ((size_t)(mblk*16 + kk)*64 + lqm*16 + lrm) * 8;
    unsigned long long* dst = (unsigned long long*)(xs0 + elem);
    __hip_atomic_store(dst,   u.u[0], __ATOMIC_RELAXED, SCOPE_AG);
    __hip_atomic_store(dst+1, u.u[1], __ATOMIC_RELAXED, SCOPE_AG);
  }

  // ---- phase 1c: w_ih1 / w_ih0 slices -> LDS in fragment order
  for (int i = tid; i < 32*64; i += NTH) {
    int kk = i >> 6, l = i & 63;
    int glr = l & 15, glq = l >> 4;
    int ggr = (glr >> 2)*NH + wg*4 + (glr & 3);
    const float* p = w_ih1 + (size_t)ggr*NH + kk*32 + glq*8;
    ((bf16x8*)sWih1)[i] = pack8(*(const float4*)p, *(const float4*)(p + 4));
  }
  for (int i = tid; i < 16*64; i += NTH) {
    int kk = i >> 6, l = i & 63;
    int glr = l & 15, glq = l >> 4;
    int ggr = (glr >> 2)*NH + wg*4 + (glr & 3);
    const float* p = w_ih0 + (size_t)ggr*NE + kk*32 + glq*8;
    ((bf16x8*)sWih0)[i] = pack8(*(const float4*)p, *(const float4*)(p + 4));
  }
  if (tid < 16) {
    int g2 = (tid >> 2)*NH + wg*4 + (tid & 3);
    sB0[tid] = b_ih0[g2] + b_hh0[g2];
    sB1[tid] = b_ih1[g2] + b_hh1[g2];
  }
  // ---- phase 1d: token histogram
  {
    int i = wg*NTH + tid;
    if (i < NB*NT) {
      int b = i >> 7;
      atomicAdd(&counts[(size_t)b*NV + x[i]], 1u);
    }
  }
  gbar_light(flagsS, 1);

  // ================= scan: 129 steps, 2 syncthreads/step =================
  // step t: waves 0-3: a0 = h0[t-1]@w_hh0^T (regs), a1 = h0[t-1]@w_ih1^T (LDS)
  //         waves 4-7: a2 = h1[t-2]@w_hh1^T (regs), aih = xs0[t]@w_ih0^T (LDS)
  // cells waves 0-3: layer0 time t (a0+aih+b0); waves 4-7: layer1 time t-1 (a1+a2+b1)
  // Each cell wave publishes its own 16 batch rows; 4th arriver sets the wg flag.
  float c_reg = 0.f;
  const int cb = (tid & 255) >> 2, cu = tid & 3;      // = (wave&3)*16 + (lane>>2)
  for (int t = 0; t <= NT; ++t) {
    // ---- head: poll readiness, then weld ----
    if (tid < NWG) {
      while (__hip_atomic_load(&flagsA[(unsigned)tid * FLAG_STRIDE],
                               __ATOMIC_RELAXED, SCOPE_AG) < (unsigned)t)
        __builtin_amdgcn_s_sleep(2);
    } else {
      unsigned need = (t > 0) ? (unsigned)(t - 1) : 0u;
      while (__hip_atomic_load(&flagsB[(unsigned)(tid - NWG) * FLAG_STRIDE],
                               __ATOMIC_RELAXED, SCOPE_AG) < need)
        __builtin_amdgcn_s_sleep(2);
    }
    __syncthreads();

    // ---- MFMA phase ----
    if (wave < 4) {
      const unsigned short* A = hist0 + (size_t)t*NBNH + (size_t)(wave*2048 + lane)*8;
      f32x4 a0 = {0.f,0.f,0.f,0.f}, a1 = {0.f,0.f,0.f,0.f};
      if (t < NT) {
        #pragma unroll
        for (int kk = 0; kk < 32; ++kk) {
          bf16x8 af = *(const bf16x8*)(A + kk*512);
          a0 = MFMA(af, breg[kk], a0);
          a1 = MFMA(af, ((const bf16x8*)sWih1)[kk*64 + lane], a1);
        }
        #pragma unroll
        for (int r = 0; r < 4; ++r) {
          sG0 [wave*16 + lq*4 + r][lr] = a0[r];
          sG1a[wave*16 + lq*4 + r][lr] = a1[r];
        }
      } else {
        #pragma unroll
        for (int kk = 0; kk < 32; ++kk)
          a1 = MFMA(*(const bf16x8*)(A + kk*512), ((const bf16x8*)sWih1)[kk*64 + lane], a1);
        #pragma unroll
        for (int r = 0; r < 4; ++r) sG1a[wave*16 + lq*4 + r][lr] = a1[r];
      }
    } else {
      if (t < NT) {
        const unsigned short* X = xs0 + ((size_t)(t*4 + (wave-4))*1024 + lane)*8;
        f32x4 ai = {0.f,0.f,0.f,0.f};
        #pragma unroll
        for (int kk = 0; kk < 16; ++kk)
          ai = MFMA(*(const bf16x8*)(X + kk*512), ((const bf16x8*)sWih0)[kk*64 + lane], ai);
        #pragma unroll
        for (int r = 0; r < 4; ++r) sGih[(wave-4)*16 + lq*4 + r][lr] = ai[r];
      }
      if (t >= 1) {
        const unsigned short* A = hist1 + (size_t)(t-1)*NBNH + (size_t)((wave-4)*2048 + lane)*8;
        f32x4 a2 = {0.f,0.f,0.f,0.f};
        #pragma unroll
        for (int kk = 0; kk < 32; ++kk)
          a2 = MFMA(*(const bf16x8*)(A + kk*512), breg[kk], a2);
        #pragma unroll
        for (int r = 0; r < 4; ++r) sG1b[(wave-4)*16 + lq*4 + r][lr] = a2[r];
      }
    }
    __syncthreads();

    // ---- cells + per-wave publish + flag ----
    if (wave < 4) {
      if (t < NT) {
        float gi = sG0[cb][cu]    + sGih[cb][cu]    + sB0[cu];
        float gf = sG0[cb][4+cu]  + sGih[cb][4+cu]  + sB0[4+cu];
        float gg = sG0[cb][8+cu]  + sGih[cb][8+cu]  + sB0[8+cu];
        float go = sG0[cb][12+cu] + sGih[cb][12+cu] + sB0[12+cu];
        float ii = sigmoidf_(gi), ff = sigmoidf_(gf), g = tanhf(gg), oo = sigmoidf_(go);
        c_reg = ff*c_reg + ii*g;
        sH0[cb][cu] = f2bf(oo * tanhf(c_reg));
        LGKM0();
        if (lane < 16) {
          unsigned long long v = *(const unsigned long long*)&sH0[(wave&3)*16 + lane][0];
          __hip_atomic_store((unsigned long long*)(hist0 + (size_t)(t+1)*NBNH + pubOff),
                             v, __ATOMIC_RELAXED, SCOPE_AG);
        }
        VM0();
        if (lane == 0) {
          unsigned old = __hip_atomic_fetch_add(&cntA, 1u, __ATOMIC_ACQ_REL, SCOPE_WG);
          if (old == 4u*(unsigned)(t+1) - 1u)
            __hip_atomic_store(&flagsA[(unsigned)wg * FLAG_STRIDE], (unsigned)(t+1),
                               __ATOMIC_RELAXED, SCOPE_AG);
        }
      }
    } else {
      if (t >= 1) {
        float gi = sG1a[cb][cu]    + sG1b[cb][cu]    + sB1[cu];
        float gf = sG1a[cb][4+cu]  + sG1b[cb][4+cu]  + sB1[4+cu];
        float gg = sG1a[cb][8+cu]  + sG1b[cb][8+cu]  + sB1[8+cu];
        float go = sG1a[cb][12+cu] + sG1b[cb][12+cu] + sB1[12+cu];
        float ii = sigmoidf_(gi), ff = sigmoidf_(gf), g = tanhf(gg), oo = sigmoidf_(go);
        c_reg = ff*c_reg + ii*g;
        sH1[cb][cu] = f2bf(oo * tanhf(c_reg));
        LGKM0();
        if (lane < 16) {
          unsigned long long v = *(const unsigned long long*)&sH1[(wave&3)*16 + lane][0];
          __hip_atomic_store((unsigned long long*)(hist1 + (size_t)t*NBNH + pubOff),
                             v, __ATOMIC_RELAXED, SCOPE_AG);
        }
        VM0();
        if (lane == 0) {
          unsigned old = __hip_atomic_fetch_add(&cntB, 1u, __ATOMIC_ACQ_REL, SCOPE_WG);
          if (old == 4u*(unsigned)t - 1u)
            __hip_atomic_store(&flagsB[(unsigned)wg * FLAG_STRIDE], (unsigned)t,
                               __ATOMIC_RELAXED, SCOPE_AG);
        }
      }
    }
  }

  // ---- FC pre-wait: hist1 slot 128 (h1[127]) published by all wgs ----
  if (tid >= NWG) {
    while (__hip_atomic_load(&flagsB[(unsigned)(tid - NWG) * FLAG_STRIDE],
                             __ATOMIC_RELAXED, SCOPE_AG) < (unsigned)NT)
      __builtin_amdgcn_s_sleep(4);
  }
  __syncthreads();

  // ---- phase 4: FC + repetition penalty (h1[127] = hist1 slot 128, fragment-major) ----
  {
    const unsigned short* ab = hist1 + (size_t)128*NBNH + (size_t)lane*8;
    int tile = wg*8 + wave;                    // 2048 waves, 2000 col-tiles of 16
    if (tile < NV/16) {
      int c0 = tile*16;
      const float* wb = fc_w + (size_t)(c0 + lr)*NH + lq*8;
      f32x4 acc[4] = {{0.f,0.f,0.f,0.f},{0.f,0.f,0.f,0.f},{0.f,0.f,0.f,0.f},{0.f,0.f,0.f,0.f}};
      #pragma unroll 4
      for (int kk = 0; kk < 32; ++kk) {
        bf16x8 bfv = pack8(*(const float4*)(wb + kk*32), *(const float4*)(wb + kk*32 + 4));
        #pragma unroll
        for (int mt = 0; mt < 4; ++mt) {
          bf16x8 af = *(const bf16x8*)(ab + (size_t)(mt*32 + kk)*512);
          acc[mt] = MFMA(af, bfv, acc[mt]);
        }
      }
      int c = c0 + lr;
      float fb = fc_b[c];
      #pragma unroll
      for (int mt = 0; mt < 4; ++mt) {
        #pragma unroll
        for (int r = 0; r < 4; ++r) {
          int b = mt*16 + lq*4 + r;
          unsigned cnt = counts[(size_t)b*NV + c];
          float v = (acc[mt][r] + fb) * exp2f(-0.26303440583379378f * (float)cnt);
          out[(size_t)b*NV + c] = v;
        }
      }
    }
  }
}

extern "C" void kernel_launch(void* const* d_in, const int* in_sizes, int n_in,
                              void* d_out, int out_size, void* d_ws, size_t ws_size,
                              hipStream_t stream) {
  const int*   x     = (const int*)  d_in[0];
  const float* emb   = (const float*)d_in[1];
  const float* w_ih0 = (const float*)d_in[2];
  const float* w_hh0 = (const float*)d_in[3];
  const float* b_ih0 = (const float*)d_in[4];
  const float* b_hh0 = (const float*)d_in[5];
  const float* w_ih1 = (const float*)d_in[6];
  const float* w_hh1 = (const float*)d_in[7];
  const float* b_ih1 = (const float*)d_in[8];
  const float* b_hh1 = (const float*)d_in[9];
  const float* fc_w  = (const float*)d_in[10];
  const float* fc_b  = (const float*)d_in[11];
  if (ws_size < WS_NEEDED) return;
  unsigned char* ws = (unsigned char*)d_ws;
  hipMemsetAsync(ws, 0, WS_H0, stream);                        // flagsS/A/B
  hipMemsetAsync(ws + WS_H0, 0, HSLOT_B, stream);              // h0 init slot (zeros)
  hipMemsetAsync(ws + WS_H1, 0, HSLOT_B, stream);              // h1 init slot (zeros)
  hipMemsetAsync(ws + WS_CNT, 0, 4u*NB*NV, stream);            // token histogram
  hipLaunchKernelGGL(lstm_all, dim3(NWG), dim3(NTH), 0, stream,
                     x, emb, w_ih0, w_hh0, b_ih0, b_hh0,
                     w_ih1, w_hh1, b_ih1, b_hh1, fc_w, fc_b,
                     (float*)d_out, (unsigned char*)d_ws);
}

// Round 9
// 1112.665 us; speedup vs baseline: 1.2067x; 1.1268x over previous
//
#include <hip/hip_runtime.h>
#include <hip/hip_bf16.h>
#include <stdint.h>

// Problem constants
#define NB 64      // batch
#define NT 128     // seq len
#define NE 512     // embed
#define NH 1024    // hidden
#define NV 32000   // vocab
#define NM (NB*NT) // 8192 flattened (t-major: m = t*64 + b)
#define NBNH (NB*NH)

// Kernel config
#define NWG 256    // one workgroup per CU, all co-resident
#define NTH 512    // 8 waves
#define FLAG_STRIDE 32u   // one flag per 128-B LLC line

// ws layout. History slots write-once per launch, FRAGMENT-MAJOR:
// element (rb,kk,lane,j) at ((rb*32+kk)*64+lane)*8+j holds
// h[rb*16+(lane&15)][kk*32+(lane>>4)*8+j].
// ALL hist lines are pre-zeroed by host memset -> LLC-resident, no HBM
// partial-line fills on the 8-B publishes (r5 counters showed ~3x write
// amplification from virgin-line fills).
#define HSLOT_B (NB*NH*2u)                      // 131072 B per history slot
#define WS_FLAGS   0u
#define WS_FLAG_B  (NWG*FLAG_STRIDE*4u)         // 32768 B
#define WS_H0      WS_FLAG_B
#define WS_H1      (WS_H0 + 129u*HSLOT_B)
#define WS_CNT     (WS_H1 + 129u*HSLOT_B)
#define WS_XS0     (WS_CNT + 4u*NB*NV)
#define WS_NEEDED  (WS_XS0 + 2u*NM*NE)

typedef __attribute__((ext_vector_type(8))) short bf16x8;
typedef __attribute__((ext_vector_type(4))) float f32x4;

#define SCOPE_AG  __HIP_MEMORY_SCOPE_AGENT

__device__ __forceinline__ unsigned short f2bf(float f) {
  unsigned u = __float_as_uint(f);
  u += 0x7FFFu + ((u >> 16) & 1u);   // round-nearest-even
  return (unsigned short)(u >> 16);
}
__device__ __forceinline__ float sigmoidf_(float x) {
  return 1.0f / (1.0f + expf(-x));
}
__device__ __forceinline__ bf16x8 pack8(float4 a, float4 b) {
  bf16x8 v;
  v[0]=(short)f2bf(a.x); v[1]=(short)f2bf(a.y); v[2]=(short)f2bf(a.z); v[3]=(short)f2bf(a.w);
  v[4]=(short)f2bf(b.x); v[5]=(short)f2bf(b.y); v[6]=(short)f2bf(b.z); v[7]=(short)f2bf(b.w);
  return v;
}

// Light grid barrier: no fences, no acquire/release cache maintenance.
// __syncthreads drains vmcnt (sc1 data stores complete at LLC) before the
// flag publish. 256 parallel pollers, one padded flag each, relaxed loads.
// SLP is a compile-time s_sleep quantum (builtin requires a constant).
template <int SLP>
__device__ __forceinline__ void gbar_light(unsigned* flags, unsigned n) {
  __syncthreads();
  if (threadIdx.x == 0)
    __hip_atomic_store(&flags[(unsigned)blockIdx.x * FLAG_STRIDE], n,
                       __ATOMIC_RELAXED, SCOPE_AG);
  if (threadIdx.x < NWG) {
    while (__hip_atomic_load(&flags[(unsigned)threadIdx.x * FLAG_STRIDE],
                             __ATOMIC_RELAXED, SCOPE_AG) < n)
      __builtin_amdgcn_s_sleep(SLP);
  }
  __syncthreads();
}

#define MFMA(a,b,c) __builtin_amdgcn_mfma_f32_16x16x32_bf16((a),(b),(c),0,0,0)

__global__ void __launch_bounds__(NTH, 2)
lstm_all(const int* __restrict__ x, const float* __restrict__ emb,
         const float* __restrict__ w_ih0, const float* __restrict__ w_hh0,
         const float* __restrict__ b_ih0, const float* __restrict__ b_hh0,
         const float* __restrict__ w_ih1, const float* __restrict__ w_hh1,
         const float* __restrict__ b_ih1, const float* __restrict__ b_hh1,
         const float* __restrict__ fc_w, const float* __restrict__ fc_b,
         float* __restrict__ out, unsigned char* __restrict__ wsb)
{
  __shared__ unsigned short sWih1[32*64*8];            // 32 KB, fragment order
  __shared__ unsigned short sWih0[16*64*8];            // 16 KB, fragment order
  __shared__ float sG0[NB][16], sGih[NB][16], sG1a[NB][16], sG1b[NB][16];
  __shared__ float sB0[16], sB1[16];
  __shared__ alignas(8) unsigned short sH0[NB][4], sH1[NB][4];

  const int wg  = blockIdx.x;
  const int tid = threadIdx.x;
  const int wave = tid >> 6, lane = tid & 63;
  const int lr = lane & 15, lq = lane >> 4;

  unsigned* flags = (unsigned*)(wsb + WS_FLAGS);
  unsigned short* hist0 = (unsigned short*)(wsb + WS_H0);
  unsigned short* hist1 = (unsigned short*)(wsb + WS_H1);
  unsigned* counts = (unsigned*)(wsb + WS_CNT);
  unsigned short* xs0 = (unsigned short*)(wsb + WS_XS0);

  // gate-row this lane's B-fragments correspond to: gate=(lr>>2), unit=(lr&3)
  const int gr = (lr >> 2)*NH + wg*4 + (lr & 3);

  // fragment-major publish offset for this wg's 4 units; batch row = lane
  const unsigned kkw = (unsigned)wg >> 3, lqw = ((unsigned)wg >> 1) & 3, j0 = ((unsigned)wg & 1)*4;
  const size_t pubOff = ((size_t)((lane>>4)*32 + kkw)*64 + lqw*16 + (lane&15))*8 + j0;

  // ---- phase 1a: step-invariant B-fragments of w_hh0 (waves 0-3) or w_hh1
  // (waves 4-7) into 128 VGPRs.
  bf16x8 breg[32];
  {
    const float* wsrc = (wave < 4 ? w_hh0 : w_hh1) + (size_t)gr*NH + lq*8;
    #pragma unroll
    for (int kk = 0; kk < 32; ++kk)
      breg[kk] = pack8(*(const float4*)(wsrc + kk*32), *(const float4*)(wsrc + kk*32 + 4));
  }

  // ---- phase 1b: gather embeddings -> xs0 (bf16, fragment-major), sc1
  for (int i = wg*NTH + tid; i < NM*(NE/8); i += NWG*NTH) {
    int m = i >> 6;
    int e8 = (i & 63) << 3;
    int t = m >> 6, b = m & 63;
    int tok = x[b*NT + t];
    const float* s = emb + (size_t)tok*NE + e8;
    union { bf16x8 v8; unsigned long long u[2]; } u;
    u.v8 = pack8(*(const float4*)s, *(const float4*)(s + 4));
    int mblk = m >> 4, lrm = m & 15;
    int kk = e8 >> 5, lqm = (e8 >> 3) & 3;
    size_t elem = ((size_t)(mblk*16 + kk)*64 + lqm*16 + lrm) * 8;
    unsigned long long* dst = (unsigned long long*)(xs0 + elem);
    __hip_atomic_store(dst,   u.u[0], __ATOMIC_RELAXED, SCOPE_AG);
    __hip_atomic_store(dst+1, u.u[1], __ATOMIC_RELAXED, SCOPE_AG);
  }

  // ---- phase 1c: w_ih1 / w_ih0 slices -> LDS in fragment order
  for (int i = tid; i < 32*64; i += NTH) {
    int kk = i >> 6, l = i & 63;
    int glr = l & 15, glq = l >> 4;
    int ggr = (glr >> 2)*NH + wg*4 + (glr & 3);
    const float* p = w_ih1 + (size_t)ggr*NH + kk*32 + glq*8;
    ((bf16x8*)sWih1)[i] = pack8(*(const float4*)p, *(const float4*)(p + 4));
  }
  for (int i = tid; i < 16*64; i += NTH) {
    int kk = i >> 6, l = i & 63;
    int glr = l & 15, glq = l >> 4;
    int ggr = (glr >> 2)*NH + wg*4 + (glr & 3);
    const float* p = w_ih0 + (size_t)ggr*NE + kk*32 + glq*8;
    ((bf16x8*)sWih0)[i] = pack8(*(const float4*)p, *(const float4*)(p + 4));
  }
  if (tid < 16) {
    int g2 = (tid >> 2)*NH + wg*4 + (tid & 3);
    sB0[tid] = b_ih0[g2] + b_hh0[g2];
    sB1[tid] = b_ih1[g2] + b_hh1[g2];
  }
  // ---- phase 1d: token histogram
  {
    int i = wg*NTH + tid;
    if (i < NB*NT) {
      int b = i >> 7;
      atomicAdd(&counts[(size_t)b*NV + x[i]], 1u);
    }
  }
  unsigned bar = 1;
  gbar_light<8>(flags, bar);

  // ---- pre-loop: ai(0) = xs0[0] @ w_ih0^T into sGih (waves 4-7; xs0 ready) ----
  if (wave >= 4) {
    const unsigned short* X = xs0 + ((size_t)(0*4 + (wave-4))*1024 + lane)*8;
    f32x4 ai = {0.f,0.f,0.f,0.f};
    #pragma unroll
    for (int kk = 0; kk < 16; ++kk)
      ai = MFMA(*(const bf16x8*)(X + kk*512), ((const bf16x8*)sWih0)[kk*64 + lane], ai);
    #pragma unroll
    for (int r = 0; r < 4; ++r) sGih[(wave-4)*16 + lq*4 + r][lr] = ai[r];
  }

  // ---- phase 3: pipelined 2-layer scan, 129 grid steps ----
  // step t: waves 0-3: a0 = h0[t-1]@w_hh0^T (regs), a1 = h0[t-1]@w_ih1^T (LDS)
  //         waves 4-7: a2 = h1[t-2]@w_hh1^T (regs)  [ai for step t was
  //         prefetched in step t-1's tail — xs0 is ready from startup]
  // cells tid<256: layer0 time t (a0+ai+b0);  tid>=256: layer1 time t-1 (a1+a2+b1)
  float c_reg = 0.f;
  const int cb = (tid & 255) >> 2, cu = tid & 3;
  for (int t = 0; t <= NT; ++t) {
    if (wave < 4) {
      // contiguous 1 KB per (wave,kk): coalesced fragment loads
      const unsigned short* A = hist0 + (size_t)t*NBNH + (size_t)(wave*2048 + lane)*8;
      f32x4 a0 = {0.f,0.f,0.f,0.f}, a1 = {0.f,0.f,0.f,0.f};
      #pragma unroll
      for (int kk = 0; kk < 32; ++kk) {
        bf16x8 af = *(const bf16x8*)(A + kk*512);
        a0 = MFMA(af, breg[kk], a0);
        a1 = MFMA(af, ((const bf16x8*)sWih1)[kk*64 + lane], a1);
      }
      #pragma unroll
      for (int r = 0; r < 4; ++r) {
        sG0 [wave*16 + lq*4 + r][lr] = a0[r];
        sG1a[wave*16 + lq*4 + r][lr] = a1[r];
      }
    } else {
      if (t >= 1) {
        const unsigned short* A = hist1 + (size_t)(t-1)*NBNH + (size_t)((wave-4)*2048 + lane)*8;
        f32x4 a2 = {0.f,0.f,0.f,0.f};
        #pragma unroll
        for (int kk = 0; kk < 32; ++kk)
          a2 = MFMA(*(const bf16x8*)(A + kk*512), breg[kk], a2);
        #pragma unroll
        for (int r = 0; r < 4; ++r) sG1b[(wave-4)*16 + lq*4 + r][lr] = a2[r];
      }
    }
    __syncthreads();
    if (tid < 256) {
      if (t < NT) {
        float gi = sG0[cb][cu]    + sGih[cb][cu]    + sB0[cu];
        float gf = sG0[cb][4+cu]  + sGih[cb][4+cu]  + sB0[4+cu];
        float gg = sG0[cb][8+cu]  + sGih[cb][8+cu]  + sB0[8+cu];
        float go = sG0[cb][12+cu] + sGih[cb][12+cu] + sB0[12+cu];
        float ii = sigmoidf_(gi), ff = sigmoidf_(gf), g = tanhf(gg), oo = sigmoidf_(go);
        c_reg = ff*c_reg + ii*g;
        sH0[cb][cu] = f2bf(oo * tanhf(c_reg));
      }
    } else {
      if (t >= 1) {
        float gi = sG1a[cb][cu]    + sG1b[cb][cu]    + sB1[cu];
        float gf = sG1a[cb][4+cu]  + sG1b[cb][4+cu]  + sB1[4+cu];
        float gg = sG1a[cb][8+cu]  + sG1b[cb][8+cu]  + sB1[8+cu];
        float go = sG1a[cb][12+cu] + sG1b[cb][12+cu] + sB1[12+cu];
        float ii = sigmoidf_(gi), ff = sigmoidf_(gf), g = tanhf(gg), oo = sigmoidf_(go);
        c_reg = ff*c_reg + ii*g;
        sH1[cb][cu] = f2bf(oo * tanhf(c_reg));
      }
    }
    __syncthreads();
    // tail: publish h slices (waves 0/1) + prefetch ai(t+1) (waves 4-7)
    if (wave == 0 && t < NT) {
      unsigned long long v = *(const unsigned long long*)&sH0[lane][0];
      __hip_atomic_store((unsigned long long*)(hist0 + (size_t)(t+1)*NBNH + pubOff),
                         v, __ATOMIC_RELAXED, SCOPE_AG);
    }
    if (wave == 1 && t >= 1) {
      unsigned long long v = *(const unsigned long long*)&sH1[lane][0];
      __hip_atomic_store((unsigned long long*)(hist1 + (size_t)t*NBNH + pubOff),
                         v, __ATOMIC_RELAXED, SCOPE_AG);
    }
    if (wave >= 4 && (t + 1) < NT) {
      const unsigned short* X = xs0 + ((size_t)((t+1)*4 + (wave-4))*1024 + lane)*8;
      f32x4 ai = {0.f,0.f,0.f,0.f};
      #pragma unroll
      for (int kk = 0; kk < 16; ++kk)
        ai = MFMA(*(const bf16x8*)(X + kk*512), ((const bf16x8*)sWih0)[kk*64 + lane], ai);
      #pragma unroll
      for (int r = 0; r < 4; ++r) sGih[(wave-4)*16 + lq*4 + r][lr] = ai[r];
    }
    gbar_light<4>(flags, ++bar);
  }

  // ---- phase 4: FC + repetition penalty (h1[127] = hist1 slot 128, fragment-major) ----
  {
    const unsigned short* ab = hist1 + (size_t)128*NBNH + (size_t)lane*8;
    int tile = wg*8 + wave;                    // 2048 waves, 2000 col-tiles of 16
    if (tile < NV/16) {
      int c0 = tile*16;
      const float* wb = fc_w + (size_t)(c0 + lr)*NH + lq*8;
      f32x4 acc[4] = {{0.f,0.f,0.f,0.f},{0.f,0.f,0.f,0.f},{0.f,0.f,0.f,0.f},{0.f,0.f,0.f,0.f}};
      #pragma unroll 4
      for (int kk = 0; kk < 32; ++kk) {
        bf16x8 bfv = pack8(*(const float4*)(wb + kk*32), *(const float4*)(wb + kk*32 + 4));
        #pragma unroll
        for (int mt = 0; mt < 4; ++mt) {
          bf16x8 af = *(const bf16x8*)(ab + (size_t)(mt*32 + kk)*512);
          acc[mt] = MFMA(af, bfv, acc[mt]);
        }
      }
      int c = c0 + lr;
      float fb = fc_b[c];
      #pragma unroll
      for (int mt = 0; mt < 4; ++mt) {
        #pragma unroll
        for (int r = 0; r < 4; ++r) {
          int b = mt*16 + lq*4 + r;
          unsigned cnt = counts[(size_t)b*NV + c];
          float v = (acc[mt][r] + fb) * exp2f(-0.26303440583379378f * (float)cnt);
          out[(size_t)b*NV + c] = v;
        }
      }
    }
  }
}

extern "C" void kernel_launch(void* const* d_in, const int* in_sizes, int n_in,
                              void* d_out, int out_size, void* d_ws, size_t ws_size,
                              hipStream_t stream) {
  const int*   x     = (const int*)  d_in[0];
  const float* emb   = (const float*)d_in[1];
  const float* w_ih0 = (const float*)d_in[2];
  const float* w_hh0 = (const float*)d_in[3];
  const float* b_ih0 = (const float*)d_in[4];
  const float* b_hh0 = (const float*)d_in[5];
  const float* w_ih1 = (const float*)d_in[6];
  const float* w_hh1 = (const float*)d_in[7];
  const float* b_ih1 = (const float*)d_in[8];
  const float* b_hh1 = (const float*)d_in[9];
  const float* fc_w  = (const float*)d_in[10];
  const float* fc_b  = (const float*)d_in[11];
  if (ws_size < WS_NEEDED) return;
  unsigned char* ws = (unsigned char*)d_ws;
  (void)hipMemsetAsync(ws + WS_FLAGS, 0, WS_FLAG_B, stream);     // barrier flags (padded)
  (void)hipMemsetAsync(ws + WS_H0, 0, 2u*129u*HSLOT_B, stream);  // ALL hist slots (fill fix)
  (void)hipMemsetAsync(ws + WS_CNT, 0, 4u*NB*NV, stream);        // token histogram
  hipLaunchKernelGGL(lstm_all, dim3(NWG), dim3(NTH), 0, stream,
                     x, emb, w_ih0, w_hh0, b_ih0, b_hh0,
                     w_ih1, w_hh1, b_ih1, b_hh1, fc_w, fc_b,
                     (float*)d_out, (unsigned char*)d_ws);
}

// Round 10
// 1077.846 us; speedup vs baseline: 1.2456x; 1.0323x over previous
//
#include <hip/hip_runtime.h>
#include <hip/hip_bf16.h>
#include <stdint.h>

// Problem constants
#define NB 64      // batch
#define NT 128     // seq len
#define NE 512     // embed
#define NH 1024    // hidden
#define NV 32000   // vocab
#define NM (NB*NT) // 8192 flattened (t-major: m = t*64 + b)
#define NBNH (NB*NH)

// Kernel config
#define NWG 256    // one workgroup per CU, all co-resident
#define NTH 512    // 8 waves
#define FLAG_STRIDE 32u   // one counter per 128-B LLC line

// ws layout. History slots write-once per launch, FRAGMENT-MAJOR:
// element (rb,kk,lane,j) at ((rb*32+kk)*64+lane)*8+j holds
// h[rb*16+(lane&15)][kk*32+(lane>>4)*8+j].
#define HSLOT_B (NB*NH*2u)                      // 131072 B per history slot
#define WS_CNTR    0u
#define WS_CNTR_B  (NWG*FLAG_STRIDE*4u)         // 32768 B (only 8 lines used)
#define WS_H0      WS_CNTR_B
#define WS_H1      (WS_H0 + 129u*HSLOT_B)
#define WS_CNT     (WS_H1 + 129u*HSLOT_B)
#define WS_XS0     (WS_CNT + 4u*NB*NV)
#define WS_NEEDED  (WS_XS0 + 2u*NM*NE)

typedef __attribute__((ext_vector_type(8))) short bf16x8;
typedef __attribute__((ext_vector_type(4))) float f32x4;

#define SCOPE_AG  __HIP_MEMORY_SCOPE_AGENT

__device__ __forceinline__ unsigned short f2bf(float f) {
  unsigned u = __float_as_uint(f);
  u += 0x7FFFu + ((u >> 16) & 1u);   // round-nearest-even
  return (unsigned short)(u >> 16);
}
__device__ __forceinline__ float sigmoidf_(float x) {
  return 1.0f / (1.0f + expf(-x));
}
__device__ __forceinline__ bf16x8 pack8(float4 a, float4 b) {
  bf16x8 v;
  v[0]=(short)f2bf(a.x); v[1]=(short)f2bf(a.y); v[2]=(short)f2bf(a.z); v[3]=(short)f2bf(a.w);
  v[4]=(short)f2bf(b.x); v[5]=(short)f2bf(b.y); v[6]=(short)f2bf(b.z); v[7]=(short)f2bf(b.w);
  return v;
}

// Counter-tree grid barrier: each wg atomically bumps one of 8 padded LLC
// counters (group = wg&7); 8 pollers per wg (wave 1, lanes 0-7) wait for all
// counters to reach 32*bar. __syncthreads (vmcnt+lgkm drain) before the add
// makes all prior sc1 data stores LLC-visible before the arrival is visible.
// Poll traffic: 2048 pollers over 8 lines (vs 65k over 256 lines with flags).
template <int SLP>
__device__ __forceinline__ void gbar_cnt(unsigned* cnt, unsigned bar) {
  __syncthreads();
  if (threadIdx.x == 0)
    __hip_atomic_fetch_add(&cnt[((unsigned)blockIdx.x & 7u) * FLAG_STRIDE], 1u,
                           __ATOMIC_RELAXED, SCOPE_AG);
  if (threadIdx.x >= 64 && threadIdx.x < 72) {
    while (__hip_atomic_load(&cnt[((unsigned)threadIdx.x - 64u) * FLAG_STRIDE],
                             __ATOMIC_RELAXED, SCOPE_AG) < 32u * bar)
      __builtin_amdgcn_s_sleep(SLP);
  }
  __syncthreads();
}

#define MFMA(a,b,c) __builtin_amdgcn_mfma_f32_16x16x32_bf16((a),(b),(c),0,0,0)

__global__ void __launch_bounds__(NTH, 2)
lstm_all(const int* __restrict__ x, const float* __restrict__ emb,
         const float* __restrict__ w_ih0, const float* __restrict__ w_hh0,
         const float* __restrict__ b_ih0, const float* __restrict__ b_hh0,
         const float* __restrict__ w_ih1, const float* __restrict__ w_hh1,
         const float* __restrict__ b_ih1, const float* __restrict__ b_hh1,
         const float* __restrict__ fc_w, const float* __restrict__ fc_b,
         float* __restrict__ out, unsigned char* __restrict__ wsb)
{
  __shared__ unsigned short sWih1[32*64*8];            // 32 KB, fragment order
  __shared__ unsigned short sWih0[16*64*8];            // 16 KB, fragment order
  __shared__ float sG0[NB][16], sGih[NB][16], sG1a[NB][16], sG1b[NB][16];
  __shared__ float sB0[16], sB1[16];

  const int wg  = blockIdx.x;
  const int tid = threadIdx.x;
  const int wave = tid >> 6, lane = tid & 63;
  const int lr = lane & 15, lq = lane >> 4;

  unsigned* cntr = (unsigned*)(wsb + WS_CNTR);
  unsigned short* hist0 = (unsigned short*)(wsb + WS_H0);
  unsigned short* hist1 = (unsigned short*)(wsb + WS_H1);
  unsigned* counts = (unsigned*)(wsb + WS_CNT);
  unsigned short* xs0 = (unsigned short*)(wsb + WS_XS0);

  // gate-row this lane's B-fragments correspond to: gate=(lr>>2), unit=(lr&3)
  const int gr = (lr >> 2)*NH + wg*4 + (lr & 3);

  // fragment-major publish offset pieces for this wg's 4 units
  const unsigned kkw = (unsigned)wg >> 3, lqw = ((unsigned)wg >> 1) & 3, j0 = ((unsigned)wg & 1)*4;
  // per-cell-thread (cb,cu) element offset; only cu==0 lanes store (8 B, 4 units)
  const int cb = (tid & 255) >> 2, cu = tid & 3;
  const size_t elemB = ((size_t)((cb >> 4)*32 + kkw)*64 + lqw*16 + (cb & 15))*8 + j0;

  // ---- phase 1a: step-invariant B-fragments of w_hh0 (waves 0-3) or w_hh1
  // (waves 4-7) into 128 VGPRs.
  bf16x8 breg[32];
  {
    const float* wsrc = (wave < 4 ? w_hh0 : w_hh1) + (size_t)gr*NH + lq*8;
    #pragma unroll
    for (int kk = 0; kk < 32; ++kk)
      breg[kk] = pack8(*(const float4*)(wsrc + kk*32), *(const float4*)(wsrc + kk*32 + 4));
  }

  // ---- phase 1b: gather embeddings -> xs0 (bf16, fragment-major), sc1
  for (int i = wg*NTH + tid; i < NM*(NE/8); i += NWG*NTH) {
    int m = i >> 6;
    int e8 = (i & 63) << 3;
    int t = m >> 6, b = m & 63;
    int tok = x[b*NT + t];
    const float* s = emb + (size_t)tok*NE + e8;
    union { bf16x8 v8; unsigned long long u[2]; } u;
    u.v8 = pack8(*(const float4*)s, *(const float4*)(s + 4));
    int mblk = m >> 4, lrm = m & 15;
    int kk = e8 >> 5, lqm = (e8 >> 3) & 3;
    size_t elem = ((size_t)(mblk*16 + kk)*64 + lqm*16 + lrm) * 8;
    unsigned long long* dst = (unsigned long long*)(xs0 + elem);
    __hip_atomic_store(dst,   u.u[0], __ATOMIC_RELAXED, SCOPE_AG);
    __hip_atomic_store(dst+1, u.u[1], __ATOMIC_RELAXED, SCOPE_AG);
  }

  // ---- phase 1c: w_ih1 / w_ih0 slices -> LDS in fragment order
  for (int i = tid; i < 32*64; i += NTH) {
    int kk = i >> 6, l = i & 63;
    int glr = l & 15, glq = l >> 4;
    int ggr = (glr >> 2)*NH + wg*4 + (glr & 3);
    const float* p = w_ih1 + (size_t)ggr*NH + kk*32 + glq*8;
    ((bf16x8*)sWih1)[i] = pack8(*(const float4*)p, *(const float4*)(p + 4));
  }
  for (int i = tid; i < 16*64; i += NTH) {
    int kk = i >> 6, l = i & 63;
    int glr = l & 15, glq = l >> 4;
    int ggr = (glr >> 2)*NH + wg*4 + (glr & 3);
    const float* p = w_ih0 + (size_t)ggr*NE + kk*32 + glq*8;
    ((bf16x8*)sWih0)[i] = pack8(*(const float4*)p, *(const float4*)(p + 4));
  }
  if (tid < 16) {
    int g2 = (tid >> 2)*NH + wg*4 + (tid & 3);
    sB0[tid] = b_ih0[g2] + b_hh0[g2];
    sB1[tid] = b_ih1[g2] + b_hh1[g2];
  }
  // ---- phase 1d: token histogram
  {
    int i = wg*NTH + tid;
    if (i < NB*NT) {
      int b = i >> 7;
      atomicAdd(&counts[(size_t)b*NV + x[i]], 1u);
    }
  }
  unsigned bar = 1;
  gbar_cnt<8>(cntr, bar);

  // ---- phase 3: pipelined 2-layer scan, 129 grid steps ----
  // step t: waves 0-3: a0 = h0[t-1]@w_hh0^T (regs), a1 = h0[t-1]@w_ih1^T (LDS)
  //         waves 4-7: a2 = h1[t-2]@w_hh1^T (regs), ai = xs0[t]@w_ih0^T (LDS)
  // cells tid<256: layer0 time t (a0+ai+b0);  tid>=256: layer1 time t-1 (a1+a2+b1)
  // Cells publish their own h directly (shfl-pack, cu==0 lane stores 8 B sc1).
  float c_reg = 0.f;
  for (int t = 0; t <= NT; ++t) {
    if (wave < 4) {
      // contiguous 1 KB per (wave,kk): coalesced fragment loads
      const unsigned short* A = hist0 + (size_t)t*NBNH + (size_t)(wave*2048 + lane)*8;
      f32x4 a0 = {0.f,0.f,0.f,0.f}, a1 = {0.f,0.f,0.f,0.f};
      if (t < NT) {
        #pragma unroll
        for (int kk = 0; kk < 32; ++kk) {
          bf16x8 af = *(const bf16x8*)(A + kk*512);
          a0 = MFMA(af, breg[kk], a0);
          a1 = MFMA(af, ((const bf16x8*)sWih1)[kk*64 + lane], a1);
        }
        #pragma unroll
        for (int r = 0; r < 4; ++r) {
          sG0 [wave*16 + lq*4 + r][lr] = a0[r];
          sG1a[wave*16 + lq*4 + r][lr] = a1[r];
        }
      } else {
        #pragma unroll
        for (int kk = 0; kk < 32; ++kk)
          a1 = MFMA(*(const bf16x8*)(A + kk*512), ((const bf16x8*)sWih1)[kk*64 + lane], a1);
        #pragma unroll
        for (int r = 0; r < 4; ++r) sG1a[wave*16 + lq*4 + r][lr] = a1[r];
      }
    } else {
      if (t >= 1) {
        const unsigned short* A = hist1 + (size_t)(t-1)*NBNH + (size_t)((wave-4)*2048 + lane)*8;
        f32x4 a2 = {0.f,0.f,0.f,0.f};
        #pragma unroll
        for (int kk = 0; kk < 32; ++kk)
          a2 = MFMA(*(const bf16x8*)(A + kk*512), breg[kk], a2);
        #pragma unroll
        for (int r = 0; r < 4; ++r) sG1b[(wave-4)*16 + lq*4 + r][lr] = a2[r];
      }
      if (t < NT) {
        const unsigned short* X = xs0 + ((size_t)(t*4 + (wave-4))*1024 + lane)*8;
        f32x4 ai = {0.f,0.f,0.f,0.f};
        #pragma unroll
        for (int kk = 0; kk < 16; ++kk)
          ai = MFMA(*(const bf16x8*)(X + kk*512), ((const bf16x8*)sWih0)[kk*64 + lane], ai);
        #pragma unroll
        for (int r = 0; r < 4; ++r) sGih[(wave-4)*16 + lq*4 + r][lr] = ai[r];
      }
    }
    __syncthreads();
    // ---- cells + direct publish ----
    if (tid < 256) {
      if (t < NT) {
        float gi = sG0[cb][cu]    + sGih[cb][cu]    + sB0[cu];
        float gf = sG0[cb][4+cu]  + sGih[cb][4+cu]  + sB0[4+cu];
        float gg = sG0[cb][8+cu]  + sGih[cb][8+cu]  + sB0[8+cu];
        float go = sG0[cb][12+cu] + sGih[cb][12+cu] + sB0[12+cu];
        float ii = sigmoidf_(gi), ff = sigmoidf_(gf), g = tanhf(gg), oo = sigmoidf_(go);
        c_reg = ff*c_reg + ii*g;
        unsigned hb = f2bf(oo * tanhf(c_reg));
        unsigned o1 = (unsigned)__shfl_down((int)hb, 1);
        unsigned o2 = (unsigned)__shfl_down((int)hb, 2);
        unsigned o3 = (unsigned)__shfl_down((int)hb, 3);
        if (cu == 0) {
          unsigned long long v = (unsigned long long)(hb | (o1 << 16))
                               | ((unsigned long long)(o2 | (o3 << 16)) << 32);
          __hip_atomic_store((unsigned long long*)(hist0 + (size_t)(t+1)*NBNH + elemB),
                             v, __ATOMIC_RELAXED, SCOPE_AG);
        }
      }
    } else {
      if (t >= 1) {
        float gi = sG1a[cb][cu]    + sG1b[cb][cu]    + sB1[cu];
        float gf = sG1a[cb][4+cu]  + sG1b[cb][4+cu]  + sB1[4+cu];
        float gg = sG1a[cb][8+cu]  + sG1b[cb][8+cu]  + sB1[8+cu];
        float go = sG1a[cb][12+cu] + sG1b[cb][12+cu] + sB1[12+cu];
        float ii = sigmoidf_(gi), ff = sigmoidf_(gf), g = tanhf(gg), oo = sigmoidf_(go);
        c_reg = ff*c_reg + ii*g;
        unsigned hb = f2bf(oo * tanhf(c_reg));
        unsigned o1 = (unsigned)__shfl_down((int)hb, 1);
        unsigned o2 = (unsigned)__shfl_down((int)hb, 2);
        unsigned o3 = (unsigned)__shfl_down((int)hb, 3);
        if (cu == 0) {
          unsigned long long v = (unsigned long long)(hb | (o1 << 16))
                               | ((unsigned long long)(o2 | (o3 << 16)) << 32);
          __hip_atomic_store((unsigned long long*)(hist1 + (size_t)t*NBNH + elemB),
                             v, __ATOMIC_RELAXED, SCOPE_AG);
        }
      }
    }
    gbar_cnt<4>(cntr, ++bar);
  }

  // ---- phase 4: FC + repetition penalty (h1[127] = hist1 slot 128, fragment-major) ----
  {
    const unsigned short* ab = hist1 + (size_t)128*NBNH + (size_t)lane*8;
    int tile = wg*8 + wave;                    // 2048 waves, 2000 col-tiles of 16
    if (tile < NV/16) {
      int c0 = tile*16;
      const float* wb = fc_w + (size_t)(c0 + lr)*NH + lq*8;
      f32x4 acc[4] = {{0.f,0.f,0.f,0.f},{0.f,0.f,0.f,0.f},{0.f,0.f,0.f,0.f},{0.f,0.f,0.f,0.f}};
      #pragma unroll 4
      for (int kk = 0; kk < 32; ++kk) {
        bf16x8 bfv = pack8(*(const float4*)(wb + kk*32), *(const float4*)(wb + kk*32 + 4));
        #pragma unroll
        for (int mt = 0; mt < 4; ++mt) {
          bf16x8 af = *(const bf16x8*)(ab + (size_t)(mt*32 + kk)*512);
          acc[mt] = MFMA(af, bfv, acc[mt]);
        }
      }
      int c = c0 + lr;
      float fb = fc_b[c];
      #pragma unroll
      for (int mt = 0; mt < 4; ++mt) {
        #pragma unroll
        for (int r = 0; r < 4; ++r) {
          int b = mt*16 + lq*4 + r;
          unsigned cnt = counts[(size_t)b*NV + c];
          float v = (acc[mt][r] + fb) * exp2f(-0.26303440583379378f * (float)cnt);
          out[(size_t)b*NV + c] = v;
        }
      }
    }
  }
}

extern "C" void kernel_launch(void* const* d_in, const int* in_sizes, int n_in,
                              void* d_out, int out_size, void* d_ws, size_t ws_size,
                              hipStream_t stream) {
  const int*   x     = (const int*)  d_in[0];
  const float* emb   = (const float*)d_in[1];
  const float* w_ih0 = (const float*)d_in[2];
  const float* w_hh0 = (const float*)d_in[3];
  const float* b_ih0 = (const float*)d_in[4];
  const float* b_hh0 = (const float*)d_in[5];
  const float* w_ih1 = (const float*)d_in[6];
  const float* w_hh1 = (const float*)d_in[7];
  const float* b_ih1 = (const float*)d_in[8];
  const float* b_hh1 = (const float*)d_in[9];
  const float* fc_w  = (const float*)d_in[10];
  const float* fc_b  = (const float*)d_in[11];
  if (ws_size < WS_NEEDED) return;
  unsigned char* ws = (unsigned char*)d_ws;
  (void)hipMemsetAsync(ws + WS_CNTR, 0, WS_CNTR_B, stream);    // barrier counters
  (void)hipMemsetAsync(ws + WS_H0, 0, HSLOT_B, stream);        // h0 init slot (zeros)
  (void)hipMemsetAsync(ws + WS_H1, 0, HSLOT_B, stream);        // h1 init slot (zeros)
  (void)hipMemsetAsync(ws + WS_CNT, 0, 4u*NB*NV, stream);      // token histogram
  hipLaunchKernelGGL(lstm_all, dim3(NWG), dim3(NTH), 0, stream,
                     x, emb, w_ih0, w_hh0, b_ih0, b_hh0,
                     w_ih1, w_hh1, b_ih1, b_hh1, fc_w, fc_b,
                     (float*)d_out, (unsigned char*)d_ws);
}

// Round 11
// 991.829 us; speedup vs baseline: 1.3537x; 1.0867x over previous
//
#include <hip/hip_runtime.h>
#include <hip/hip_bf16.h>
#include <stdint.h>

// Problem constants
#define NB 64      // batch
#define NT 128     // seq len
#define NE 512     // embed
#define NH 1024    // hidden
#define NV 32000   // vocab
#define NM (NB*NT) // 8192 flattened (t-major: m = t*64 + b)

// Kernel config: 2 independent batch-groups of 128 wgs. Group g = wg>>7 owns
// batches [32g, 32g+32); each wg computes 8 hidden units x 32 batches.
#define NWG 256
#define NTH 512
#define WPG 128            // wgs per group
#define FLAG_STRIDE 32u    // one flag per 128-B LLC line

// History half-slots per group, write-once, FRAGMENT-MAJOR:
// shorts offset (rb,kk,lane,j) = ((rb*32+kk)*64+lane)*8+j holds
// h[g*32 + rb*16 + (lane&15)][kk*32 + (lane>>4)*8 + j].
#define HS_SHORTS 32768u                        // 64 KB half-slot
#define GSTRIDE_SH (129u*HS_SHORTS)             // shorts per group hist
#define WS_FLAGS_S 0u
#define WS_FLAGS_G 32768u
#define WS_H0      65536u
#define WS_H1      (WS_H0 + 2u*129u*65536u)     // +16,908,288
#define WS_CNT     (WS_H1 + 2u*129u*65536u)
#define WS_XS0     (WS_CNT + 4u*NB*NV)
#define WS_NEEDED  (WS_XS0 + 2u*NM*NE)

typedef __attribute__((ext_vector_type(8))) short bf16x8;
typedef __attribute__((ext_vector_type(4))) float f32x4;

#define SCOPE_AG  __HIP_MEMORY_SCOPE_AGENT

__device__ __forceinline__ unsigned short f2bf(float f) {
  unsigned u = __float_as_uint(f);
  u += 0x7FFFu + ((u >> 16) & 1u);   // round-nearest-even
  return (unsigned short)(u >> 16);
}
__device__ __forceinline__ float sigmoidf_(float x) {
  return 1.0f / (1.0f + expf(-x));
}
__device__ __forceinline__ bf16x8 pack8(float4 a, float4 b) {
  bf16x8 v;
  v[0]=(short)f2bf(a.x); v[1]=(short)f2bf(a.y); v[2]=(short)f2bf(a.z); v[3]=(short)f2bf(a.w);
  v[4]=(short)f2bf(b.x); v[5]=(short)f2bf(b.y); v[6]=(short)f2bf(b.z); v[7]=(short)f2bf(b.w);
  return v;
}

#define MFMA(a,b,c) __builtin_amdgcn_mfma_f32_16x16x32_bf16((a),(b),(c),0,0,0)

__global__ void __launch_bounds__(NTH, 2)
lstm_all(const int* __restrict__ x, const float* __restrict__ emb,
         const float* __restrict__ w_ih0, const float* __restrict__ w_hh0,
         const float* __restrict__ b_ih0, const float* __restrict__ b_hh0,
         const float* __restrict__ w_ih1, const float* __restrict__ w_hh1,
         const float* __restrict__ b_ih1, const float* __restrict__ b_hh1,
         const float* __restrict__ fc_w, const float* __restrict__ fc_b,
         float* __restrict__ out, unsigned char* __restrict__ wsb)
{
  // LDS ~145 KB: weight slices in MFMA-fragment order [(ct)][kk][lane][8]
  __shared__ unsigned short sWih1[2*32*64*8];   // 64 KB: w_ih1 ct0+ct1
  __shared__ unsigned short sWhh0c1[32*64*8];   // 32 KB: w_hh0 ct1
  __shared__ unsigned short sWhh1c1[32*64*8];   // 32 KB: w_hh1 ct1
  __shared__ float sG0[32][32], sG1a[32][32], sG1b[32][32], sGih[32][32];
  __shared__ float sB0[32], sB1[32];
  __shared__ alignas(16) unsigned short sH0[32][8], sH1[32][8];

  const int wg  = blockIdx.x;
  const int tid = threadIdx.x;
  const int wave = tid >> 6, lane = tid & 63;
  const int lr = lane & 15, lq = lane >> 4;
  const int g  = wg >> 7;          // batch group
  const int wgl = wg & 127;        // wg within group (unit base = wgl*8)

  unsigned* flagsS = (unsigned*)(wsb + WS_FLAGS_S);
  unsigned* gf     = (unsigned*)(wsb + WS_FLAGS_G) + (unsigned)g*WPG*FLAG_STRIDE;
  unsigned short* h0g = (unsigned short*)(wsb + WS_H0) + (size_t)g*GSTRIDE_SH;
  unsigned short* h1g = (unsigned short*)(wsb + WS_H1) + (size_t)g*GSTRIDE_SH;
  unsigned* counts = (unsigned*)(wsb + WS_CNT);
  unsigned short* xs0 = (unsigned short*)(wsb + WS_XS0);

  // ---- breg: step-invariant B-fragments (ct0 of the wave's weight matrix) ----
  // w2/w3: w_hh0 ct0; w0/w1: w_hh1 ct0; w4/w5: w_ih0 ct0(kk<16)+ct1(kk>=16).
  bf16x8 breg[32];
  {
    const int ggr0 = (lr >> 3)*NH + wgl*8 + (lr & 7);          // col c = lr
    const int ggr1 = (2 + (lr >> 3))*NH + wgl*8 + (lr & 7);    // col c = 16+lr
    if (wave == 2 || wave == 3) {
      const float* src = w_hh0 + (size_t)ggr0*NH + lq*8;
      #pragma unroll
      for (int kk = 0; kk < 32; ++kk)
        breg[kk] = pack8(*(const float4*)(src + kk*32), *(const float4*)(src + kk*32 + 4));
    } else if (wave == 0 || wave == 1) {
      const float* src = w_hh1 + (size_t)ggr0*NH + lq*8;
      #pragma unroll
      for (int kk = 0; kk < 32; ++kk)
        breg[kk] = pack8(*(const float4*)(src + kk*32), *(const float4*)(src + kk*32 + 4));
    } else if (wave == 4 || wave == 5) {
      const float* s0 = w_ih0 + (size_t)ggr0*NE + lq*8;
      const float* s1 = w_ih0 + (size_t)ggr1*NE + lq*8;
      #pragma unroll
      for (int kk = 0; kk < 16; ++kk) {
        breg[kk]    = pack8(*(const float4*)(s0 + kk*32), *(const float4*)(s0 + kk*32 + 4));
        breg[16+kk] = pack8(*(const float4*)(s1 + kk*32), *(const float4*)(s1 + kk*32 + 4));
      }
    }
  }

  // ---- gather embeddings -> xs0 (bf16, per-group fragment-major), sc1 ----
  for (int i = wg*NTH + tid; i < NM*(NE/8); i += NWG*NTH) {
    int m = i >> 6;
    int e8 = (i & 63) << 3;
    int t = m >> 6, b = m & 63;
    int tok = x[b*NT + t];
    const float* s = emb + (size_t)tok*NE + e8;
    union { bf16x8 v8; unsigned long long u[2]; } u;
    u.v8 = pack8(*(const float4*)s, *(const float4*)(s + 4));
    int gg = b >> 5, bb = b & 31;
    size_t off = ((size_t)((gg*NT + t)*2 + (bb >> 4)))*8192
               + ((size_t)((e8 >> 5)*64 + ((e8 >> 3) & 3)*16 + (bb & 15)))*8;
    unsigned long long* dst = (unsigned long long*)(xs0 + off);
    __hip_atomic_store(dst,   u.u[0], __ATOMIC_RELAXED, SCOPE_AG);
    __hip_atomic_store(dst+1, u.u[1], __ATOMIC_RELAXED, SCOPE_AG);
  }

  // ---- weight slices -> LDS in fragment order ----
  for (int i = tid; i < 2*32*64; i += NTH) {        // sWih1 ct0+ct1
    int ct = i >> 11, kk = (i >> 6) & 31, l = i & 63;
    int glr = l & 15, glq = l >> 4;
    int c = ct*16 + glr;
    int ggr = (c >> 3)*NH + wgl*8 + (c & 7);
    const float* p = w_ih1 + (size_t)ggr*NH + kk*32 + glq*8;
    ((bf16x8*)sWih1)[i] = pack8(*(const float4*)p, *(const float4*)(p + 4));
  }
  for (int i = tid; i < 32*64; i += NTH) {          // sWhh0c1 / sWhh1c1
    int kk = i >> 6, l = i & 63;
    int glr = l & 15, glq = l >> 4;
    int ggr = (2 + (glr >> 3))*NH + wgl*8 + (glr & 7);   // col c = 16+glr
    const float* p0 = w_hh0 + (size_t)ggr*NH + kk*32 + glq*8;
    const float* p1 = w_hh1 + (size_t)ggr*NH + kk*32 + glq*8;
    ((bf16x8*)sWhh0c1)[i] = pack8(*(const float4*)p0, *(const float4*)(p0 + 4));
    ((bf16x8*)sWhh1c1)[i] = pack8(*(const float4*)p1, *(const float4*)(p1 + 4));
  }
  if (tid < 32) {
    int g2 = (tid >> 3)*NH + wgl*8 + (tid & 7);
    sB0[tid] = b_ih0[g2] + b_hh0[g2];
    sB1[tid] = b_ih1[g2] + b_hh1[g2];
  }
  // ---- token histogram ----
  {
    int i = wg*NTH + tid;
    if (i < NB*NT) {
      int b = i >> 7;
      atomicAdd(&counts[(size_t)b*NV + x[i]], 1u);
    }
  }
  // ---- startup: GLOBAL barrier (gather written by all wgs) ----
  __syncthreads();
  if (tid == 0)
    __hip_atomic_store(&flagsS[(unsigned)wg * FLAG_STRIDE], 1u, __ATOMIC_RELAXED, SCOPE_AG);
  if (tid < NWG) {
    while (__hip_atomic_load(&flagsS[(unsigned)tid * FLAG_STRIDE], __ATOMIC_RELAXED, SCOPE_AG) < 1u)
      __builtin_amdgcn_s_sleep(8);
  }
  __syncthreads();

  // ---- scan: 129 steps, per-group barrier ----
  // w2/w3 (rb=w-2): A=hist0[t] -> a0ct0(breg) a0ct1(LDS) a1ct0 a1ct1(LDS)
  // w0/w1 (rb=w):   A=hist1[t-1] -> a2ct0(breg) a2ct1(LDS)
  // w4/w5 (rb=w-4): A=xs[t] -> ai ct0/ct1 (breg)
  // cells tid<256: layer0 t; tid>=256: layer1 t-1. w6/w7 publish.
  float c_reg = 0.f;
  const int cbb = (tid & 255) >> 3, cu8 = tid & 7;
  for (int t = 0; t <= NT; ++t) {
    if (wave == 2 || wave == 3) {
      const int rb = wave - 2;
      const unsigned short* A = h0g + (size_t)t*HS_SHORTS + rb*16384 + lane*8;
      f32x4 a00 = {0.f,0.f,0.f,0.f}, a01 = {0.f,0.f,0.f,0.f};
      f32x4 a10 = {0.f,0.f,0.f,0.f}, a11 = {0.f,0.f,0.f,0.f};
      #pragma unroll
      for (int kk = 0; kk < 32; ++kk) {
        bf16x8 af = *(const bf16x8*)(A + kk*512);
        a00 = MFMA(af, breg[kk], a00);
        a01 = MFMA(af, ((const bf16x8*)sWhh0c1)[kk*64 + lane], a01);
        a10 = MFMA(af, ((const bf16x8*)sWih1)[kk*64 + lane], a10);
        a11 = MFMA(af, ((const bf16x8*)sWih1)[(32+kk)*64 + lane], a11);
      }
      #pragma unroll
      for (int r = 0; r < 4; ++r) {
        int row = rb*16 + lq*4 + r;
        sG0 [row][lr]    = a00[r];
        sG0 [row][16+lr] = a01[r];
        sG1a[row][lr]    = a10[r];
        sG1a[row][16+lr] = a11[r];
      }
    } else if (wave == 0 || wave == 1) {
      if (t >= 1) {
        const int rb = wave;
        const unsigned short* A = h1g + (size_t)(t-1)*HS_SHORTS + rb*16384 + lane*8;
        f32x4 a20 = {0.f,0.f,0.f,0.f}, a21 = {0.f,0.f,0.f,0.f};
        #pragma unroll
        for (int kk = 0; kk < 32; ++kk) {
          bf16x8 af = *(const bf16x8*)(A + kk*512);
          a20 = MFMA(af, breg[kk], a20);
          a21 = MFMA(af, ((const bf16x8*)sWhh1c1)[kk*64 + lane], a21);
        }
        #pragma unroll
        for (int r = 0; r < 4; ++r) {
          int row = rb*16 + lq*4 + r;
          sG1b[row][lr]    = a20[r];
          sG1b[row][16+lr] = a21[r];
        }
      }
    } else if (wave == 4 || wave == 5) {
      if (t < NT) {
        const int rb = wave - 4;
        const unsigned short* A = xs0 + ((size_t)((g*NT + t)*2 + rb))*8192 + lane*8;
        f32x4 ai0 = {0.f,0.f,0.f,0.f}, ai1 = {0.f,0.f,0.f,0.f};
        #pragma unroll
        for (int kk = 0; kk < 16; ++kk) {
          bf16x8 af = *(const bf16x8*)(A + kk*512);
          ai0 = MFMA(af, breg[kk], ai0);
          ai1 = MFMA(af, breg[16+kk], ai1);
        }
        #pragma unroll
        for (int r = 0; r < 4; ++r) {
          int row = rb*16 + lq*4 + r;
          sGih[row][lr]    = ai0[r];
          sGih[row][16+lr] = ai1[r];
        }
      }
    }
    __syncthreads();
    // ---- cells ----
    if (tid < 256) {
      if (t < NT) {
        float gi = sG0[cbb][cu8]    + sGih[cbb][cu8]    + sB0[cu8];
        float gf = sG0[cbb][8+cu8]  + sGih[cbb][8+cu8]  + sB0[8+cu8];
        float gg = sG0[cbb][16+cu8] + sGih[cbb][16+cu8] + sB0[16+cu8];
        float go = sG0[cbb][24+cu8] + sGih[cbb][24+cu8] + sB0[24+cu8];
        float ii = sigmoidf_(gi), ff = sigmoidf_(gf), gv = tanhf(gg), oo = sigmoidf_(go);
        c_reg = ff*c_reg + ii*gv;
        sH0[cbb][cu8] = f2bf(oo * tanhf(c_reg));
      }
    } else {
      if (t >= 1) {
        float gi = sG1a[cbb][cu8]    + sG1b[cbb][cu8]    + sB1[cu8];
        float gf = sG1a[cbb][8+cu8]  + sG1b[cbb][8+cu8]  + sB1[8+cu8];
        float gg = sG1a[cbb][16+cu8] + sG1b[cbb][16+cu8] + sB1[16+cu8];
        float go = sG1a[cbb][24+cu8] + sG1b[cbb][24+cu8] + sB1[24+cu8];
        float ii = sigmoidf_(gi), ff = sigmoidf_(gf), gv = tanhf(gg), oo = sigmoidf_(go);
        c_reg = ff*c_reg + ii*gv;
        sH1[cbb][cu8] = f2bf(oo * tanhf(c_reg));
      }
    }
    __syncthreads();
    // ---- publish (w6: hist0 slot t+1, w7: hist1 slot t), 8 B sc1/lane ----
    if (wave == 6 && t < NT) {
      int bb = lane >> 1, j0 = (lane & 1)*4;
      unsigned long long v = *(const unsigned long long*)&sH0[bb][j0];
      size_t off = ((size_t)(((bb >> 4)*32 + (wgl >> 2))*64 + (wgl & 3)*16 + (bb & 15)))*8 + j0;
      __hip_atomic_store((unsigned long long*)(h0g + (size_t)(t+1)*HS_SHORTS + off),
                         v, __ATOMIC_RELAXED, SCOPE_AG);
    }
    if (wave == 7 && t >= 1) {
      int bb = lane >> 1, j0 = (lane & 1)*4;
      unsigned long long v = *(const unsigned long long*)&sH1[bb][j0];
      size_t off = ((size_t)(((bb >> 4)*32 + (wgl >> 2))*64 + (wgl & 3)*16 + (bb & 15)))*8 + j0;
      __hip_atomic_store((unsigned long long*)(h1g + (size_t)t*HS_SHORTS + off),
                         v, __ATOMIC_RELAXED, SCOPE_AG);
    }
    // ---- per-group barrier (r5 skeleton: flag + 128 parallel pollers) ----
    __syncthreads();
    if (tid == 0)
      __hip_atomic_store(&gf[(unsigned)wgl * FLAG_STRIDE], (unsigned)(t+1),
                         __ATOMIC_RELAXED, SCOPE_AG);
    if (tid < WPG) {
      while (__hip_atomic_load(&gf[(unsigned)tid * FLAG_STRIDE],
                               __ATOMIC_RELAXED, SCOPE_AG) < (unsigned)(t+1))
        __builtin_amdgcn_s_sleep(4);
    }
    __syncthreads();
  }

  // ---- FC + repetition penalty (group's h1[127] = hist1 slot 128) ----
  {
    const unsigned short* ab = h1g + (size_t)128*HS_SHORTS + lane*8;
    for (int tile = wgl*8 + wave; tile < NV/16; tile += WPG*8) {
      int c0 = tile*16;
      const float* wb = fc_w + (size_t)(c0 + lr)*NH + lq*8;
      f32x4 acc0 = {0.f,0.f,0.f,0.f}, acc1 = {0.f,0.f,0.f,0.f};
      #pragma unroll 4
      for (int kk = 0; kk < 32; ++kk) {
        bf16x8 bfv = pack8(*(const float4*)(wb + kk*32), *(const float4*)(wb + kk*32 + 4));
        acc0 = MFMA(*(const bf16x8*)(ab + kk*512),         bfv, acc0);
        acc1 = MFMA(*(const bf16x8*)(ab + 16384 + kk*512), bfv, acc1);
      }
      int c = c0 + lr;
      float fb = fc_b[c];
      #pragma unroll
      for (int r = 0; r < 4; ++r) {
        int b0 = g*32 + lq*4 + r;          // rb = 0
        int b1 = b0 + 16;                  // rb = 1
        unsigned cnt0 = counts[(size_t)b0*NV + c];
        unsigned cnt1 = counts[(size_t)b1*NV + c];
        out[(size_t)b0*NV + c] = (acc0[r] + fb) * exp2f(-0.26303440583379378f * (float)cnt0);
        out[(size_t)b1*NV + c] = (acc1[r] + fb) * exp2f(-0.26303440583379378f * (float)cnt1);
      }
    }
  }
}

extern "C" void kernel_launch(void* const* d_in, const int* in_sizes, int n_in,
                              void* d_out, int out_size, void* d_ws, size_t ws_size,
                              hipStream_t stream) {
  const int*   x     = (const int*)  d_in[0];
  const float* emb   = (const float*)d_in[1];
  const float* w_ih0 = (const float*)d_in[2];
  const float* w_hh0 = (const float*)d_in[3];
  const float* b_ih0 = (const float*)d_in[4];
  const float* b_hh0 = (const float*)d_in[5];
  const float* w_ih1 = (const float*)d_in[6];
  const float* w_hh1 = (const float*)d_in[7];
  const float* b_ih1 = (const float*)d_in[8];
  const float* b_hh1 = (const float*)d_in[9];
  const float* fc_w  = (const float*)d_in[10];
  const float* fc_b  = (const float*)d_in[11];
  if (ws_size < WS_NEEDED) return;
  unsigned char* ws = (unsigned char*)d_ws;
  (void)hipMemsetAsync(ws, 0, WS_H0, stream);                          // both flag arrays
  (void)hipMemsetAsync(ws + WS_H0, 0, 65536, stream);                  // hist0 g0 slot 0
  (void)hipMemsetAsync(ws + WS_H0 + 129u*65536u, 0, 65536, stream);    // hist0 g1 slot 0
  (void)hipMemsetAsync(ws + WS_H1, 0, 65536, stream);                  // hist1 g0 slot 0
  (void)hipMemsetAsync(ws + WS_H1 + 129u*65536u, 0, 65536, stream);    // hist1 g1 slot 0
  (void)hipMemsetAsync(ws + WS_CNT, 0, 4u*NB*NV, stream);              // token histogram
  hipLaunchKernelGGL(lstm_all, dim3(NWG), dim3(NTH), 0, stream,
                     x, emb, w_ih0, w_hh0, b_ih0, b_hh0,
                     w_ih1, w_hh1, b_ih1, b_hh1, fc_w, fc_b,
                     (float*)d_out, (unsigned char*)d_ws);
}